// Round 20
// baseline (163.726 us; speedup 1.0000x reference)
//
#include <hip/hip_runtime.h>

#define C_IN  128
#define C_HID 128
#define C_OUT 64
#define TILE  4096
#define BCAP  6144   // per-bucket LDS staging capacity (mean 4082, sd ~64; fallback if exceeded)

typedef __attribute__((ext_vector_type(8))) short short8;
typedef __attribute__((ext_vector_type(4))) float f32x4;

// bf16 helpers (RNE)
__device__ __forceinline__ unsigned f2bf(float f) {
    unsigned u = __float_as_uint(f);
    return (u + 0x7FFF + ((u >> 16) & 1)) >> 16;
}
__device__ __forceinline__ float bflo(unsigned t) { return __uint_as_float(t << 16); }
__device__ __forceinline__ float bfhi(unsigned t) { return __uint_as_float(t & 0xFFFF0000u); }

// 256-wide exclusive block scan (Hillis-Steele in LDS). After return, s[255] = total.
__device__ __forceinline__ int block_exscan(int v, int* s) {
    const int tid = threadIdx.x;
    s[tid] = v;
    __syncthreads();
    #pragma unroll
    for (int off = 1; off < 256; off <<= 1) {
        int t = (tid >= off) ? s[tid - off] : 0;
        __syncthreads();
        s[tid] += t;
        __syncthreads();
    }
    return s[tid] - v;
}

// 512-wide variant (values beyond the first 256 lanes are zero-padded by callers).
__device__ __forceinline__ int block_exscan512(int v, int* s) {
    const int tid = threadIdx.x;
    s[tid] = v;
    __syncthreads();
    #pragma unroll
    for (int off = 1; off < 512; off <<= 1) {
        int t = (tid >= off) ? s[tid - off] : 0;
        __syncthreads();
        s[tid] += t;
        __syncthreads();
    }
    return s[tid] - v;
}

// ================= per-tile bucket histogram =================

__global__ __launch_bounds__(256) void k_histo(const int* __restrict__ ei, int* __restrict__ histT,
                                               int E, int NT, int NB) {
    __shared__ int h[256];
    const int t = blockIdx.x;
    const int tid = threadIdx.x;
    h[tid] = 0;
    __syncthreads();
    const int end = min((t + 1) * TILE, E);
    for (int i = t * TILE + tid; i < end; i += 256)
        atomicAdd(&h[ei[E + i] >> 8], 1);              // LDS atomic
    __syncthreads();
    if (tid < NB) histT[tid * NT + t] = h[tid];
}

// ================= per-bucket tile scan: tilePrefix[b][t] (exclusive over t) + BT[b] =================

__global__ __launch_bounds__(256) void k_tilescan(const int* __restrict__ histT,
                                                  int* __restrict__ tilePrefix,
                                                  int* __restrict__ BT, int NT, int NB) {
    __shared__ int s[256];
    const int b = blockIdx.x;
    const int tid = threadIdx.x;
    int v = (tid < NT) ? histT[b * NT + tid] : 0;
    int ex = block_exscan(v, s);
    if (tid < NT) tilePrefix[b * NT + tid] = ex;
    if (tid == 255) BT[b] = s[255];                    // bucket total
}

// ================= reorder: scatter packed (src<<8)|(dst&255) into per-bucket runs =================

__global__ __launch_bounds__(512) void k_reorder(const int* __restrict__ ei,
                                                 const int* __restrict__ tilePrefix,
                                                 const int* __restrict__ BT,
                                                 unsigned* __restrict__ tmp,
                                                 int E, int NT, int NB) {
    __shared__ int s[512];
    __shared__ int cur[256];
    const int t = blockIdx.x;
    const int tid = threadIdx.x;
    int v = (tid < NB) ? BT[tid] : 0;
    int base = block_exscan512(v, s);
    if (tid < NB) cur[tid] = base + tilePrefix[tid * NT + t];
    __syncthreads();
    const int end = min((t + 1) * TILE, E);
    for (int i = t * TILE + tid; i < end; i += 512) {
        int d = ei[E + i];
        int sv = ei[i];
        int p = atomicAdd(&cur[d >> 8], 1);            // LDS atomic, global slot
        tmp[p] = ((unsigned)sv << 8) | (unsigned)(d & 255);
    }
}

// ================= per-bucket finalize (512 thr, LDS-staged) =================

__global__ __launch_bounds__(512) void k_bucket(const unsigned* __restrict__ tmp,
                                                const int* __restrict__ BT,
                                                int* __restrict__ row_ptr,
                                                float* __restrict__ dinv,
                                                int* __restrict__ csr_src,
                                                int E, int NB, int n) {
    __shared__ int sA[512], ssc[512];
    __shared__ int c[256], lcur[256];
    __shared__ unsigned ebuf[BCAP];
    __shared__ int obuf[BCAP];
    const int b = blockIdx.x;
    const int tid = threadIdx.x;

    int v = (tid < NB) ? BT[tid] : 0;
    (void)block_exscan512(v, sA);                      // sA[i] = inclusive scan of BT
    const int vb = BT[b];
    const int rbeg = sA[b] - vb;                       // exclusive prefix at b
    const bool fits = (vb <= BCAP);

    if (tid < 256) c[tid] = 0;
    __syncthreads();
    if (fits) {
        for (int i = tid; i < vb; i += 512) {
            unsigned w = tmp[rbeg + i];
            ebuf[i] = w;
            atomicAdd(&c[w & 255], 1);                 // LDS histogram
        }
    } else {
        for (int i = tid; i < vb; i += 512)
            atomicAdd(&c[tmp[rbeg + i] & 255], 1);
    }
    __syncthreads();

    int cv = (tid < 256) ? c[tid] : 0;
    int ex = block_exscan512(cv, ssc);                 // local exclusive offsets

    if (tid < 256) {
        const int d = b * 256 + tid;
        if (d < n) {
            row_ptr[d] = rbeg + ex;
            dinv[d] = rsqrtf((float)(c[tid] + 1));     // +1 self-loop
            if (d == n - 1) row_ptr[n] = E;
        }
        lcur[tid] = ex;                                // LOCAL cursor
    }
    __syncthreads();

    if (fits) {
        for (int i = tid; i < vb; i += 512) {
            unsigned w = ebuf[i];
            int p = atomicAdd(&lcur[w & 255], 1);      // LDS atomic, local position
            obuf[p] = (int)(w >> 8);
        }
        __syncthreads();
        for (int i = tid; i < vb; i += 512)
            csr_src[rbeg + i] = obuf[i];               // coalesced dense write
    } else {
        for (int i = tid; i < vb; i += 512) {
            unsigned w = tmp[rbeg + i];
            int p = atomicAdd(&lcur[w & 255], 1);
            csr_src[rbeg + p] = (int)(w >> 8);
        }
    }
}

// ================= MFMA GEMM: H'bf16[M,N] = dinv[row] * (X[M,128] @ Wf32[128,N]) =================

template<int N, bool F32IN>
__global__ __launch_bounds__(256) void k_gemm_mfma(const void* __restrict__ Xraw,
                                                   const float* __restrict__ W,
                                                   const float* __restrict__ dinv,
                                                   unsigned short* __restrict__ H, int M) {
    constexpr int K = 128;
    constexpr int LDT = K + 8;                 // pad: 2-way-free b128 reads
    __shared__ unsigned short sWt[N * LDT];

    const int tid = threadIdx.x;
    constexpr int NLOG = (N == 128) ? 7 : 6;
    for (int idx = tid; idx < K * N; idx += 256) {
        int k = idx >> NLOG, c = idx & (N - 1);
        sWt[c * LDT + k] = (unsigned short)f2bf(W[idx]);
    }
    __syncthreads();

    const int wave = __builtin_amdgcn_readfirstlane(tid >> 6);
    const int lane = tid & 63;
    const int m0 = blockIdx.x * 64 + wave * 16;
    if (m0 >= M) return;                        // no syncthreads after this point

    const int arow = lane & 15;
    const int koff = (lane >> 4) * 8;           // 0,8,16,24 -> f32 addr 32B-aligned

    short8 a[4];
    if (F32IN) {
        const float* apf = (const float*)Xraw + (size_t)(m0 + arow) * K + koff;
        #pragma unroll
        for (int q = 0; q < 4; ++q) {
            float4 v0 = *(const float4*)(apf + q * 32);
            float4 v1 = *(const float4*)(apf + q * 32 + 4);
            short8 t;
            t[0] = (short)f2bf(v0.x); t[1] = (short)f2bf(v0.y);
            t[2] = (short)f2bf(v0.z); t[3] = (short)f2bf(v0.w);
            t[4] = (short)f2bf(v1.x); t[5] = (short)f2bf(v1.y);
            t[6] = (short)f2bf(v1.z); t[7] = (short)f2bf(v1.w);
            a[q] = t;
        }
    } else {
        const unsigned short* ap = (const unsigned short*)Xraw + (size_t)(m0 + arow) * K + koff;
        #pragma unroll
        for (int q = 0; q < 4; ++q) a[q] = *(const short8*)(ap + q * 32);
    }

    const int row0 = m0 + (lane >> 4) * 4;
    const float4 dv = *(const float4*)(dinv + row0);   // row0 % 4 == 0, dinv 16B-aligned

    #pragma unroll
    for (int ct = 0; ct < N / 16; ++ct) {
        const int bcol = ct * 16 + (lane & 15);
        const unsigned short* bp = &sWt[bcol * LDT + koff];
        f32x4 acc = {0.f, 0.f, 0.f, 0.f};
        #pragma unroll
        for (int q = 0; q < 4; ++q) {
            short8 bq = *(const short8*)(bp + q * 32);
            acc = __builtin_amdgcn_mfma_f32_16x16x32_bf16(a[q], bq, acc, 0, 0, 0);
        }
        const int col = ct * 16 + (lane & 15);
        #pragma unroll
        for (int r = 0; r < 4; ++r) {
            float dr = (r == 0) ? dv.x : (r == 1) ? dv.y : (r == 2) ? dv.z : dv.w;
            H[(size_t)(row0 + r) * N + col] = (unsigned short)f2bf(acc[r] * dr);
        }
    }
}

// ================= agg128 channel-sliced: wave = (node, 32-ch slice); XCD-affine slices ====
// slice = blockIdx&3 -> XCDs {slice, slice+4} (round-robin heuristic). Each XCD's L2 only
// holds its 64B-per-row h-slice (3.2MB) instead of all of h (12.8MB): FETCH 112 -> ~55MB.
// 16-lane groups gather different edges (4 edges/instruction, one 64B line each);
// shfl_xor(16/32) tree-reduces the 4 partial sums; lanes<16 write the output slice.

__global__ __launch_bounds__(256) void k_agg128s(const unsigned* __restrict__ hu,
                                                 const int* __restrict__ row_ptr,
                                                 const int* __restrict__ csr_src,
                                                 const float* __restrict__ dinv,
                                                 const float* __restrict__ bias,
                                                 unsigned* __restrict__ agg, int n) {
    const int lane = threadIdx.x & 63;
    const int wv = __builtin_amdgcn_readfirstlane(threadIdx.x >> 6);
    const int slice = blockIdx.x & 3;
    const int v = (blockIdx.x >> 2) * 4 + wv;
    if (v >= n) return;

    const int grp = lane >> 4;                   // edge sub-group 0..3
    const int cl  = lane & 15;                   // uint channel within slice
    const unsigned* hsl = hu + slice * 16;       // column-slice base

    const int e0 = row_ptr[v], e1 = row_ptr[v + 1];
    const float dd = dinv[v];

    float a0 = 0.f, a1 = 0.f;
    if (grp == 0) {                              // self term counted once
        unsigned t = hsl[(size_t)v * 64 + cl];
        a0 = bflo(t); a1 = bfhi(t);
    }

    int j0 = e0;
    for (; j0 + 16 <= e1; j0 += 16) {            // 4 gather-steps in flight
        int s0 = csr_src[j0 + grp];
        int s1 = csr_src[j0 + 4 + grp];
        int s2 = csr_src[j0 + 8 + grp];
        int s3 = csr_src[j0 + 12 + grp];
        unsigned t0 = hsl[(size_t)s0 * 64 + cl];
        unsigned t1 = hsl[(size_t)s1 * 64 + cl];
        unsigned t2 = hsl[(size_t)s2 * 64 + cl];
        unsigned t3 = hsl[(size_t)s3 * 64 + cl];
        a0 += bflo(t0); a1 += bfhi(t0);
        a0 += bflo(t1); a1 += bfhi(t1);
        a0 += bflo(t2); a1 += bfhi(t2);
        a0 += bflo(t3); a1 += bfhi(t3);
    }
    for (; j0 < e1; j0 += 4) {                   // tail: 4 edges/step, predicated
        int idx = j0 + grp;
        bool ok = (idx < e1);
        int s = ok ? csr_src[idx] : v;           // exec-masked load; clamp keeps gather in-bounds
        unsigned t = hsl[(size_t)s * 64 + cl];
        float m = ok ? 1.f : 0.f;
        a0 = fmaf(m, bflo(t), a0);
        a1 = fmaf(m, bfhi(t), a1);
    }

    // reduce the 4 per-group partials
    a0 += __shfl_xor(a0, 16); a1 += __shfl_xor(a1, 16);
    a0 += __shfl_xor(a0, 32); a1 += __shfl_xor(a1, 32);

    if (grp == 0) {
        float2 bv = ((const float2*)bias)[slice * 16 + cl];
        float ox = a0 * dd + bv.x;
        float oy = a1 * dd + bv.y;
        ox = fmaxf(ox, 0.f); oy = fmaxf(oy, 0.f);                   // RELU (layer-1 epilogue)
        agg[(size_t)v * 64 + slice * 16 + cl] = (f2bf(oy) << 16) | f2bf(ox);  // bf16 packed
    }
}

// ================= aggregation: G=1 — one wave per node (R16-proven; used for C=64) =================

template<int C, bool RELU, bool OUTBF>
__global__ __launch_bounds__(256) void k_agg(const void* __restrict__ hraw,
                                             const int* __restrict__ row_ptr,
                                             const int* __restrict__ csr_src,
                                             const float* __restrict__ dinv,
                                             const float* __restrict__ bias,
                                             void* __restrict__ agg, int n) {
    constexpr int U = 16;
    constexpr int VPC = C / 64;          // 2 (C=128) or 1 (C=64)
    const int lane = threadIdx.x & 63;
    const int wv = __builtin_amdgcn_readfirstlane(threadIdx.x >> 6);
    const int v = blockIdx.x * 4 + wv;
    if (v >= n) return;

    const unsigned*       hu = (const unsigned*)hraw;        // C=128 view
    const unsigned short* hs = (const unsigned short*)hraw;  // C=64 view

    const int e0 = row_ptr[v], e1 = row_ptr[v + 1];
    const float dd = dinv[v];

    float acc[VPC];
    if (VPC == 2) {
        unsigned t = hu[(size_t)v * 64 + lane];
        acc[0] = bflo(t);
        acc[1] = bfhi(t);
    } else {
        acc[0] = bflo(hs[(size_t)v * 64 + lane]);
    }

    int j0 = e0;
    for (; j0 + U <= e1; j0 += U) {              // full batches: no masks, no multiplies
        int ss[U];
        #pragma unroll
        for (int u = 0; u < U; ++u) ss[u] = csr_src[j0 + u];   // contiguous scalar loads
        float hv[U][VPC];
        #pragma unroll
        for (int u = 0; u < U; ++u) {
            if (VPC == 2) {
                unsigned t = hu[(size_t)ss[u] * 64 + lane];
                hv[u][0] = bflo(t);
                hv[u][1] = bfhi(t);
            } else {
                hv[u][0] = bflo(hs[(size_t)ss[u] * 64 + lane]);
            }
        }
        #pragma unroll
        for (int u = 0; u < U; ++u) {
            acc[0] += hv[u][0];
            if (VPC == 2) acc[1] += hv[u][1];
        }
    }
    if (j0 < e1) {                               // one boundary batch per node
        int ss[U];
        #pragma unroll
        for (int u = 0; u < U; ++u) {
            int sraw = csr_src[j0 + u];          // <=60B overread into next ws buffer
            ss[u] = (j0 + u < e1) ? sraw : v;    // clamp OOB to self row (L1-hot)
        }
        float hv[U][VPC];
        #pragma unroll
        for (int u = 0; u < U; ++u) {
            if (VPC == 2) {
                unsigned t = hu[(size_t)ss[u] * 64 + lane];
                hv[u][0] = bflo(t);
                hv[u][1] = bfhi(t);
            } else {
                hv[u][0] = bflo(hs[(size_t)ss[u] * 64 + lane]);
            }
        }
        #pragma unroll
        for (int u = 0; u < U; ++u) {
            float m = (j0 + u < e1) ? 1.f : 0.f;
            acc[0] = fmaf(m, hv[u][0], acc[0]);
            if (VPC == 2) acc[1] = fmaf(m, hv[u][1], acc[1]);
        }
    }

    if (VPC == 2) {
        float2 bv = ((const float2*)bias)[lane];
        float ox = acc[0] * dd + bv.x;
        float oy = acc[1] * dd + bv.y;
        if (RELU) { ox = fmaxf(ox, 0.f); oy = fmaxf(oy, 0.f); }
        if (OUTBF) {
            ((unsigned*)agg)[(size_t)v * 64 + lane] = (f2bf(oy) << 16) | f2bf(ox);
        } else {
            ((float2*)agg)[(size_t)v * 64 + lane] = make_float2(ox, oy);
        }
    } else {
        float o = acc[0] * dd + bias[lane];
        if (RELU) o = fmaxf(o, 0.f);
        if (OUTBF) ((unsigned short*)agg)[(size_t)v * 64 + lane] = (unsigned short)f2bf(o);
        else       ((float*)agg)[(size_t)v * 64 + lane] = o;
    }
}

// ================= launch =================

extern "C" void kernel_launch(void* const* d_in, const int* in_sizes, int n_in,
                              void* d_out, int out_size, void* d_ws, size_t ws_size,
                              hipStream_t stream) {
    const float* x  = (const float*)d_in[0];
    const int*   ei = (const int*)d_in[1];
    const float* W1 = (const float*)d_in[2];
    const float* b1 = (const float*)d_in[3];
    const float* W2 = (const float*)d_in[4];
    const float* b2 = (const float*)d_in[5];
    float* out = (float*)d_out;

    const int N = in_sizes[0] / C_IN;   // 50000
    const int E = in_sizes[1] / 2;      // 800000
    const int NT = (E + TILE - 1) / TILE;   // 196 tiles   (<=256 required)
    const int NB = (N + 255) >> 8;          // 196 buckets (<=256 required)
    const int M2 = NB * NT;

    // 16B-aligned workspace layout
    char* base = (char*)d_ws;
    size_t off = 0;
    auto alloc = [&](size_t bytes) {
        char* q = base + off;
        off = (off + bytes + 15) & ~(size_t)15;
        return q;
    };
    int*   histT      = (int*)  alloc((size_t)M2 * 4);
    int*   tilePrefix = (int*)  alloc((size_t)M2 * 4);
    int*   BT         = (int*)  alloc(256 * 4);
    unsigned* tmp     = (unsigned*)alloc((size_t)E * 4);
    int*   row_ptr    = (int*)  alloc((size_t)(N + 1) * 4);
    float* dinv       = (float*)alloc((size_t)N * 4);
    int*   csr_src    = (int*)  alloc((size_t)E * 4);
    unsigned short* h    = (unsigned short*)alloc((size_t)N * C_HID * 2);  // bf16 h' / h2'
    unsigned short* agg1 = (unsigned short*)alloc((size_t)N * C_HID * 2);  // bf16 agg1
    unsigned short* h2   = h;  // layer-2 h' reuses h (dead after agg128)

    dim3 blk(256);

    // CSR build (no global atomics)
    k_histo   <<<NT, blk, 0, stream>>>(ei, histT, E, NT, NB);
    k_tilescan<<<NB, blk, 0, stream>>>(histT, tilePrefix, BT, NT, NB);
    k_reorder <<<NT, dim3(512), 0, stream>>>(ei, tilePrefix, BT, tmp, E, NT, NB);
    k_bucket  <<<NB, dim3(512), 0, stream>>>(tmp, BT, row_ptr, dinv, csr_src, E, NB, N);

    const int gblocks = (N + 63) / 64;
    const int ablocks = (N + 3) / 4;      // C=64 agg: 4 waves x 1 node per block
    const int asblocks = ((N + 3) / 4) * 4;  // sliced agg128: x4 channel slices

    // layer 1: h' = dinv * bf16(x @ W1) ; agg1 = bf16(relu(dinv*(sum h') + b1)), channel-sliced
    k_gemm_mfma<C_HID, true><<<gblocks, blk, 0, stream>>>(x, W1, dinv, h, N);
    k_agg128s<<<asblocks, blk, 0, stream>>>((const unsigned*)h, row_ptr, csr_src, dinv, b1,
                                            (unsigned*)agg1, N);

    // layer 2: h2' = dinv * bf16(agg1 @ W2) ; out = dinv*(sum h2') + b2
    k_gemm_mfma<C_OUT, false><<<gblocks, blk, 0, stream>>>(agg1, W2, dinv, h2, N);
    k_agg<C_OUT, false, false><<<ablocks, blk, 0, stream>>>(h2, row_ptr, csr_src, dinv, b2, out, N);
}

// Round 21
// 110.804 us; speedup vs baseline: 1.4776x; 1.4776x over previous
//
#include <hip/hip_runtime.h>

#define C_IN  128
#define C_HID 128
#define C_OUT 64
#define TILE  4096
#define BCAP  6144   // per-bucket LDS staging capacity (mean 4082, sd ~64; fallback if exceeded)

typedef __attribute__((ext_vector_type(8))) short short8;
typedef __attribute__((ext_vector_type(4))) float f32x4;

// bf16 helpers (RNE)
__device__ __forceinline__ unsigned f2bf(float f) {
    unsigned u = __float_as_uint(f);
    return (u + 0x7FFF + ((u >> 16) & 1)) >> 16;
}
__device__ __forceinline__ float bflo(unsigned t) { return __uint_as_float(t << 16); }
__device__ __forceinline__ float bfhi(unsigned t) { return __uint_as_float(t & 0xFFFF0000u); }

// 256-wide exclusive block scan (Hillis-Steele in LDS). After return, s[255] = total.
__device__ __forceinline__ int block_exscan(int v, int* s) {
    const int tid = threadIdx.x;
    s[tid] = v;
    __syncthreads();
    #pragma unroll
    for (int off = 1; off < 256; off <<= 1) {
        int t = (tid >= off) ? s[tid - off] : 0;
        __syncthreads();
        s[tid] += t;
        __syncthreads();
    }
    return s[tid] - v;
}

// 512-wide variant (values beyond the first 256 lanes are zero-padded by callers).
__device__ __forceinline__ int block_exscan512(int v, int* s) {
    const int tid = threadIdx.x;
    s[tid] = v;
    __syncthreads();
    #pragma unroll
    for (int off = 1; off < 512; off <<= 1) {
        int t = (tid >= off) ? s[tid - off] : 0;
        __syncthreads();
        s[tid] += t;
        __syncthreads();
    }
    return s[tid] - v;
}

// ================= per-tile bucket histogram =================

__global__ __launch_bounds__(256) void k_histo(const int* __restrict__ ei, int* __restrict__ histT,
                                               int E, int NT, int NB) {
    __shared__ int h[256];
    const int t = blockIdx.x;
    const int tid = threadIdx.x;
    h[tid] = 0;
    __syncthreads();
    const int end = min((t + 1) * TILE, E);
    for (int i = t * TILE + tid; i < end; i += 256)
        atomicAdd(&h[ei[E + i] >> 8], 1);              // LDS atomic
    __syncthreads();
    if (tid < NB) histT[tid * NT + t] = h[tid];
}

// ================= per-bucket tile scan: tilePrefix[b][t] (exclusive over t) + BT[b] =================

__global__ __launch_bounds__(256) void k_tilescan(const int* __restrict__ histT,
                                                  int* __restrict__ tilePrefix,
                                                  int* __restrict__ BT, int NT, int NB) {
    __shared__ int s[256];
    const int b = blockIdx.x;
    const int tid = threadIdx.x;
    int v = (tid < NT) ? histT[b * NT + tid] : 0;
    int ex = block_exscan(v, s);
    if (tid < NT) tilePrefix[b * NT + tid] = ex;
    if (tid == 255) BT[b] = s[255];                    // bucket total
}

// ================= reorder: scatter packed (src<<8)|(dst&255) into per-bucket runs =================
// 512 threads: 8 waves/block for latency hiding. Global offsets reconstructed in-block.

__global__ __launch_bounds__(512) void k_reorder(const int* __restrict__ ei,
                                                 const int* __restrict__ tilePrefix,
                                                 const int* __restrict__ BT,
                                                 unsigned* __restrict__ tmp,
                                                 int E, int NT, int NB) {
    __shared__ int s[512];
    __shared__ int cur[256];
    const int t = blockIdx.x;
    const int tid = threadIdx.x;
    int v = (tid < NB) ? BT[tid] : 0;
    int base = block_exscan512(v, s);
    if (tid < NB) cur[tid] = base + tilePrefix[tid * NT + t];
    __syncthreads();
    const int end = min((t + 1) * TILE, E);
    for (int i = t * TILE + tid; i < end; i += 512) {
        int d = ei[E + i];
        int sv = ei[i];
        int p = atomicAdd(&cur[d >> 8], 1);            // LDS atomic, global slot
        tmp[p] = ((unsigned)sv << 8) | (unsigned)(d & 255);
    }
}

// ================= per-bucket finalize (512 thr, LDS-staged) =================

__global__ __launch_bounds__(512) void k_bucket(const unsigned* __restrict__ tmp,
                                                const int* __restrict__ BT,
                                                int* __restrict__ row_ptr,
                                                float* __restrict__ dinv,
                                                int* __restrict__ csr_src,
                                                int E, int NB, int n) {
    __shared__ int sA[512], ssc[512];
    __shared__ int c[256], lcur[256];
    __shared__ unsigned ebuf[BCAP];
    __shared__ int obuf[BCAP];
    const int b = blockIdx.x;
    const int tid = threadIdx.x;

    int v = (tid < NB) ? BT[tid] : 0;
    (void)block_exscan512(v, sA);                      // sA[i] = inclusive scan of BT
    const int vb = BT[b];
    const int rbeg = sA[b] - vb;                       // exclusive prefix at b
    const bool fits = (vb <= BCAP);

    if (tid < 256) c[tid] = 0;
    __syncthreads();
    if (fits) {
        for (int i = tid; i < vb; i += 512) {
            unsigned w = tmp[rbeg + i];
            ebuf[i] = w;
            atomicAdd(&c[w & 255], 1);                 // LDS histogram
        }
    } else {
        for (int i = tid; i < vb; i += 512)
            atomicAdd(&c[tmp[rbeg + i] & 255], 1);
    }
    __syncthreads();

    int cv = (tid < 256) ? c[tid] : 0;
    int ex = block_exscan512(cv, ssc);                 // local exclusive offsets

    if (tid < 256) {
        const int d = b * 256 + tid;
        if (d < n) {
            row_ptr[d] = rbeg + ex;
            dinv[d] = rsqrtf((float)(c[tid] + 1));     // +1 self-loop
            if (d == n - 1) row_ptr[n] = E;
        }
        lcur[tid] = ex;                                // LOCAL cursor
    }
    __syncthreads();

    if (fits) {
        for (int i = tid; i < vb; i += 512) {
            unsigned w = ebuf[i];
            int p = atomicAdd(&lcur[w & 255], 1);      // LDS atomic, local position
            obuf[p] = (int)(w >> 8);
        }
        __syncthreads();
        for (int i = tid; i < vb; i += 512)
            csr_src[rbeg + i] = obuf[i];               // coalesced dense write
    } else {
        for (int i = tid; i < vb; i += 512) {
            unsigned w = tmp[rbeg + i];
            int p = atomicAdd(&lcur[w & 255], 1);
            csr_src[rbeg + p] = (int)(w >> 8);
        }
    }
}

// ================= MFMA GEMM: H'bf16[M,N] = dinv[row] * (X[M,128] @ Wf32[128,N]) =================
// 256 thr = 4 waves; wave w owns 16-row strip (M % 16 == 0). mfma_f32_16x16x32_bf16.
// F32IN: A-fragments read from f32 x directly (2 aligned float4/lane) and converted
// in-register with the same RNE f2bf — bitwise-identical to a separate cvt pass,
// but skips the 38MB xb round-trip entirely.

template<int N, bool F32IN>
__global__ __launch_bounds__(256) void k_gemm_mfma(const void* __restrict__ Xraw,
                                                   const float* __restrict__ W,
                                                   const float* __restrict__ dinv,
                                                   unsigned short* __restrict__ H, int M) {
    constexpr int K = 128;
    constexpr int LDT = K + 8;                 // pad: 2-way-free b128 reads
    __shared__ unsigned short sWt[N * LDT];

    const int tid = threadIdx.x;
    constexpr int NLOG = (N == 128) ? 7 : 6;
    for (int idx = tid; idx < K * N; idx += 256) {
        int k = idx >> NLOG, c = idx & (N - 1);
        sWt[c * LDT + k] = (unsigned short)f2bf(W[idx]);
    }
    __syncthreads();

    const int wave = __builtin_amdgcn_readfirstlane(tid >> 6);
    const int lane = tid & 63;
    const int m0 = blockIdx.x * 64 + wave * 16;
    if (m0 >= M) return;                        // no syncthreads after this point

    const int arow = lane & 15;
    const int koff = (lane >> 4) * 8;           // 0,8,16,24 -> f32 addr 32B-aligned

    short8 a[4];
    if (F32IN) {
        const float* apf = (const float*)Xraw + (size_t)(m0 + arow) * K + koff;
        #pragma unroll
        for (int q = 0; q < 4; ++q) {
            float4 v0 = *(const float4*)(apf + q * 32);
            float4 v1 = *(const float4*)(apf + q * 32 + 4);
            short8 t;
            t[0] = (short)f2bf(v0.x); t[1] = (short)f2bf(v0.y);
            t[2] = (short)f2bf(v0.z); t[3] = (short)f2bf(v0.w);
            t[4] = (short)f2bf(v1.x); t[5] = (short)f2bf(v1.y);
            t[6] = (short)f2bf(v1.z); t[7] = (short)f2bf(v1.w);
            a[q] = t;
        }
    } else {
        const unsigned short* ap = (const unsigned short*)Xraw + (size_t)(m0 + arow) * K + koff;
        #pragma unroll
        for (int q = 0; q < 4; ++q) a[q] = *(const short8*)(ap + q * 32);
    }

    const int row0 = m0 + (lane >> 4) * 4;
    const float4 dv = *(const float4*)(dinv + row0);   // row0 % 4 == 0, dinv 16B-aligned

    #pragma unroll
    for (int ct = 0; ct < N / 16; ++ct) {
        const int bcol = ct * 16 + (lane & 15);
        const unsigned short* bp = &sWt[bcol * LDT + koff];
        f32x4 acc = {0.f, 0.f, 0.f, 0.f};
        #pragma unroll
        for (int q = 0; q < 4; ++q) {
            short8 bq = *(const short8*)(bp + q * 32);
            acc = __builtin_amdgcn_mfma_f32_16x16x32_bf16(a[q], bq, acc, 0, 0, 0);
        }
        const int col = ct * 16 + (lane & 15);
        #pragma unroll
        for (int r = 0; r < 4; ++r) {
            float dr = (r == 0) ? dv.x : (r == 1) ? dv.y : (r == 2) ? dv.z : dv.w;
            H[(size_t)(row0 + r) * N + col] = (unsigned short)f2bf(acc[r] * dr);
        }
    }
}

// ================= aggregation: G=1 — one wave per node, unweighted sum (R16-proven) =================

template<int C, bool RELU, bool OUTBF>
__global__ __launch_bounds__(256) void k_agg(const void* __restrict__ hraw,
                                             const int* __restrict__ row_ptr,
                                             const int* __restrict__ csr_src,
                                             const float* __restrict__ dinv,
                                             const float* __restrict__ bias,
                                             void* __restrict__ agg, int n) {
    constexpr int U = 16;
    constexpr int VPC = C / 64;          // 2 (C=128) or 1 (C=64)
    const int lane = threadIdx.x & 63;
    const int wv = __builtin_amdgcn_readfirstlane(threadIdx.x >> 6);
    const int v = blockIdx.x * 4 + wv;
    if (v >= n) return;

    const unsigned*       hu = (const unsigned*)hraw;        // C=128 view
    const unsigned short* hs = (const unsigned short*)hraw;  // C=64 view

    const int e0 = row_ptr[v], e1 = row_ptr[v + 1];
    const float dd = dinv[v];

    float acc[VPC];
    if (VPC == 2) {
        unsigned t = hu[(size_t)v * 64 + lane];
        acc[0] = bflo(t);
        acc[1] = bfhi(t);
    } else {
        acc[0] = bflo(hs[(size_t)v * 64 + lane]);
    }

    int j0 = e0;
    for (; j0 + U <= e1; j0 += U) {              // full batches: no masks, no multiplies
        int ss[U];
        #pragma unroll
        for (int u = 0; u < U; ++u) ss[u] = csr_src[j0 + u];   // contiguous scalar loads
        float hv[U][VPC];
        #pragma unroll
        for (int u = 0; u < U; ++u) {
            if (VPC == 2) {
                unsigned t = hu[(size_t)ss[u] * 64 + lane];
                hv[u][0] = bflo(t);
                hv[u][1] = bfhi(t);
            } else {
                hv[u][0] = bflo(hs[(size_t)ss[u] * 64 + lane]);
            }
        }
        #pragma unroll
        for (int u = 0; u < U; ++u) {
            acc[0] += hv[u][0];
            if (VPC == 2) acc[1] += hv[u][1];
        }
    }
    if (j0 < e1) {                               // one boundary batch per node
        int ss[U];
        #pragma unroll
        for (int u = 0; u < U; ++u) {
            int sraw = csr_src[j0 + u];          // <=60B overread into next ws buffer
            ss[u] = (j0 + u < e1) ? sraw : v;    // clamp OOB to self row (L1-hot)
        }
        float hv[U][VPC];
        #pragma unroll
        for (int u = 0; u < U; ++u) {
            if (VPC == 2) {
                unsigned t = hu[(size_t)ss[u] * 64 + lane];
                hv[u][0] = bflo(t);
                hv[u][1] = bfhi(t);
            } else {
                hv[u][0] = bflo(hs[(size_t)ss[u] * 64 + lane]);
            }
        }
        #pragma unroll
        for (int u = 0; u < U; ++u) {
            float m = (j0 + u < e1) ? 1.f : 0.f;
            acc[0] = fmaf(m, hv[u][0], acc[0]);
            if (VPC == 2) acc[1] = fmaf(m, hv[u][1], acc[1]);
        }
    }

    if (VPC == 2) {
        float2 bv = ((const float2*)bias)[lane];   // bias[2l], bias[2l+1]
        float ox = acc[0] * dd + bv.x;
        float oy = acc[1] * dd + bv.y;
        if (RELU) { ox = fmaxf(ox, 0.f); oy = fmaxf(oy, 0.f); }
        if (OUTBF) {
            ((unsigned*)agg)[(size_t)v * 64 + lane] = (f2bf(oy) << 16) | f2bf(ox);
        } else {
            ((float2*)agg)[(size_t)v * 64 + lane] = make_float2(ox, oy);
        }
    } else {
        float o = acc[0] * dd + bias[lane];
        if (RELU) o = fmaxf(o, 0.f);
        if (OUTBF) ((unsigned short*)agg)[(size_t)v * 64 + lane] = (unsigned short)f2bf(o);
        else       ((float*)agg)[(size_t)v * 64 + lane] = o;
    }
}

// ================= launch =================

extern "C" void kernel_launch(void* const* d_in, const int* in_sizes, int n_in,
                              void* d_out, int out_size, void* d_ws, size_t ws_size,
                              hipStream_t stream) {
    const float* x  = (const float*)d_in[0];
    const int*   ei = (const int*)d_in[1];
    const float* W1 = (const float*)d_in[2];
    const float* b1 = (const float*)d_in[3];
    const float* W2 = (const float*)d_in[4];
    const float* b2 = (const float*)d_in[5];
    float* out = (float*)d_out;

    const int N = in_sizes[0] / C_IN;   // 50000
    const int E = in_sizes[1] / 2;      // 800000
    const int NT = (E + TILE - 1) / TILE;   // 196 tiles   (<=256 required)
    const int NB = (N + 255) >> 8;          // 196 buckets (<=256 required)
    const int M2 = NB * NT;

    // 16B-aligned workspace layout
    char* base = (char*)d_ws;
    size_t off = 0;
    auto alloc = [&](size_t bytes) {
        char* q = base + off;
        off = (off + bytes + 15) & ~(size_t)15;
        return q;
    };
    int*   histT      = (int*)  alloc((size_t)M2 * 4);
    int*   tilePrefix = (int*)  alloc((size_t)M2 * 4);
    int*   BT         = (int*)  alloc(256 * 4);
    unsigned* tmp     = (unsigned*)alloc((size_t)E * 4);
    int*   row_ptr    = (int*)  alloc((size_t)(N + 1) * 4);
    float* dinv       = (float*)alloc((size_t)N * 4);
    int*   csr_src    = (int*)  alloc((size_t)E * 4);
    unsigned short* h    = (unsigned short*)alloc((size_t)N * C_HID * 2);  // bf16 h' / h2'
    unsigned short* agg1 = (unsigned short*)alloc((size_t)N * C_HID * 2);  // bf16 agg1
    unsigned short* h2   = h;  // layer-2 h' reuses h (dead after agg128)

    dim3 blk(256);

    // CSR build (no global atomics)
    k_histo   <<<NT, blk, 0, stream>>>(ei, histT, E, NT, NB);
    k_tilescan<<<NB, blk, 0, stream>>>(histT, tilePrefix, BT, NT, NB);
    k_reorder <<<NT, dim3(512), 0, stream>>>(ei, tilePrefix, BT, tmp, E, NT, NB);
    k_bucket  <<<NB, dim3(512), 0, stream>>>(tmp, BT, row_ptr, dinv, csr_src, E, NB, N);

    const int gblocks = (N + 63) / 64;
    const int ablocks = (N + 3) / 4;     // 4 waves x 1 node per block

    // layer 1: h' = dinv * bf16(x @ W1) (f32 A-read, in-register cvt) ; agg1 = bf16(relu(...))
    k_gemm_mfma<C_HID, true><<<gblocks, blk, 0, stream>>>(x, W1, dinv, h, N);
    k_agg<C_HID, true, true><<<ablocks, blk, 0, stream>>>(h, row_ptr, csr_src, dinv, b1, agg1, N);

    // layer 2: h2' = dinv * bf16(agg1 @ W2) ; out = dinv*(sum h2') + b2
    k_gemm_mfma<C_OUT, false><<<gblocks, blk, 0, stream>>>(agg1, W2, dinv, h2, N);
    k_agg<C_OUT, false, false><<<ablocks, blk, 0, stream>>>(h2, row_ptr, csr_src, dinv, b2, out, N);
}